// Round 13
// baseline (98.634 us; speedup 1.0000x reference)
//
#include <hip/hip_runtime.h>
#include <hip/hip_bf16.h>

#define N_NODES 100000
#define N_EDGES 1600000
#define D_IN    128
#define D_HID   16
#define D_OUT   32

#define BSHIFT 8
#define BNODES 256                 // nodes per bucket
#define NB 391                     // ceil(100000/256)
#define NBPAD 512
#define SCHUNK 4096                // edges per sort block
#define SBLOCKS 391                // ceil(1600000/4096)
#define MMBLOCKS 782               // mm1: 2 nodes/thread, 4 lanes/node
#define SLAB 4608                  // slab slots per bucket (mean 4096, +8 sigma)
#define NOSTRIDE 257               // node_off stride per bucket (256 + sentinel)

// bf16x2 helpers -------------------------------------------------------------
__device__ inline float bf_lo(unsigned dw) { return __uint_as_float(dw << 16); }
__device__ inline float bf_hi(unsigned dw) { return __uint_as_float(dw & 0xffff0000u); }
__device__ inline unsigned bf_pack(float f0, float f1) {
    union { __hip_bfloat16 h[2]; unsigned u; } pu;
    pu.h[0] = __float2bfloat16(f0);
    pu.h[1] = __float2bfloat16(f1);
    return pu.u;
}
__device__ inline void acc4(float* a, uint2 w) {
    a[0] += bf_lo(w.x); a[1] += bf_hi(w.x);
    a[2] += bf_lo(w.y); a[3] += bf_hi(w.y);
}

// ---------------------------------------------------------------------------
// K1: Y = feat @ W1 -> packed bf16. 2 nodes/thread, 4 jq lanes/node:
// halved LDS W-reads vs 1-node/thread; 8 KB LDS -> full occupancy.
// Also zeroes the slab cursors (block b < NB, thread 0) -- race-free since
// sortscatter is a later kernel on the same stream.
// ---------------------------------------------------------------------------
__global__ __launch_bounds__(256) void k_mm1(const float* __restrict__ feat,
                                             const float* __restrict__ W1,
                                             unsigned* __restrict__ Yu,
                                             int* __restrict__ cursor) {
    __shared__ float sW[D_IN * D_HID];  // 8 KB
    int tid = threadIdx.x, blk = blockIdx.x;
    for (int i = tid; i < D_IN * D_HID; i += 256) sW[i] = W1[i];
    if (tid == 0 && blk < NB) cursor[blk] = 0;
    __syncthreads();

    int gid = blk * 256 + tid;
    int p = gid >> 2;          // node pair
    int jq = gid & 3;          // output quad
    int n0 = p * 2, n1 = p * 2 + 1;
    if (n0 >= N_NODES) return;
    bool has1 = (n1 < N_NODES);

    const float4* f40 = (const float4*)(feat + (size_t)n0 * D_IN);
    const float4* f41 = (const float4*)(feat + (size_t)n1 * D_IN);
    const float4* sW4 = (const float4*)sW;

    float4 acc0 = make_float4(0.f, 0.f, 0.f, 0.f);
    float4 acc1 = make_float4(0.f, 0.f, 0.f, 0.f);
#pragma unroll 4
    for (int kq = 0; kq < 32; ++kq) {
        float4 f0 = f40[kq];
        float4 f1 = has1 ? f41[kq] : make_float4(0.f, 0.f, 0.f, 0.f);
        int k0 = kq * 4;
        float4 w0 = sW4[(k0 + 0) * 4 + jq];
        float4 w1 = sW4[(k0 + 1) * 4 + jq];
        float4 w2 = sW4[(k0 + 2) * 4 + jq];
        float4 w3 = sW4[(k0 + 3) * 4 + jq];
        acc0.x += f0.x * w0.x + f0.y * w1.x + f0.z * w2.x + f0.w * w3.x;
        acc0.y += f0.x * w0.y + f0.y * w1.y + f0.z * w2.y + f0.w * w3.y;
        acc0.z += f0.x * w0.z + f0.y * w1.z + f0.z * w2.z + f0.w * w3.z;
        acc0.w += f0.x * w0.w + f0.y * w1.w + f0.z * w2.w + f0.w * w3.w;
        acc1.x += f1.x * w0.x + f1.y * w1.x + f1.z * w2.x + f1.w * w3.x;
        acc1.y += f1.x * w0.y + f1.y * w1.y + f1.z * w2.y + f1.w * w3.y;
        acc1.z += f1.x * w0.z + f1.y * w1.z + f1.z * w2.z + f1.w * w3.z;
        acc1.w += f1.x * w0.w + f1.y * w1.w + f1.z * w2.w + f1.w * w3.w;
    }
    uint2 o0;
    o0.x = bf_pack(acc0.x, acc0.y);
    o0.y = bf_pack(acc0.z, acc0.w);
    ((uint2*)(Yu + (size_t)n0 * 8))[jq] = o0;
    if (has1) {
        uint2 o1;
        o1.x = bf_pack(acc1.x, acc1.y);
        o1.y = bf_pack(acc1.z, acc1.w);
        ((uint2*)(Yu + (size_t)n1 * 8))[jq] = o1;
    }
}

// ---------------------------------------------------------------------------
// K2: block-local counting sort + run-reserved slab writeout. Cursors start
// at 0; slot base = b*SLAB + reserved offset. ~10.5-edge runs.
// pairs value = (src << 8) | (dst & 255).
// ---------------------------------------------------------------------------
__global__ __launch_bounds__(256) void k_sortscatter(const int* __restrict__ src,
                                                     const int* __restrict__ dst,
                                                     int* __restrict__ cursor,
                                                     unsigned* __restrict__ pairs) {
    __shared__ int hist[NBPAD];         // 2 KB, reused as placement counters
    __shared__ int lbase[NBPAD];        // 2 KB
    __shared__ int gbase[NB];           // 1.6 KB
    __shared__ int tscan[256];          // 1 KB
    __shared__ unsigned sorted[SCHUNK]; // 16 KB
    __shared__ unsigned short bId[SCHUNK]; // 8 KB

    int tid = threadIdx.x;
    int base = blockIdx.x * SCHUNK;
    int nval = N_EDGES - base;
    if (nval > SCHUNK) nval = SCHUNK;

    for (int i = tid; i < NBPAD; i += 256) hist[i] = 0;
    __syncthreads();

    int varr[16], barr[16];
#pragma unroll
    for (int k = 0; k < 16; ++k) {
        int e = base + k * 256 + tid;
        if (e < N_EDGES) {
            int s = src[e], d = dst[e];
            varr[k] = (s << BSHIFT) | (d & (BNODES - 1));
            int b = d >> BSHIFT;
            barr[k] = b;
            atomicAdd(&hist[b], 1);
        } else {
            barr[k] = -1;
        }
    }
    __syncthreads();

    int i0 = tid * 2;
    int h0 = hist[i0], h1 = hist[i0 + 1];
    int lsum = h0 + h1;
    tscan[tid] = lsum;
    __syncthreads();
#pragma unroll
    for (int off = 1; off < 256; off <<= 1) {
        int x = (tid >= off) ? tscan[tid - off] : 0;
        __syncthreads();
        tscan[tid] += x;
        __syncthreads();
    }
    int excl = tscan[tid] - lsum;
    lbase[i0 + 0] = excl;
    lbase[i0 + 1] = excl + h0;
    __syncthreads();

    for (int i = tid; i < NB; i += 256) {
        int c = hist[i];
        if (c > 0) gbase[i] = i * SLAB + atomicAdd(&cursor[i], c);
    }
    __syncthreads();
    for (int i = tid; i < NBPAD; i += 256) hist[i] = 0;   // -> placement cnt
    __syncthreads();

#pragma unroll
    for (int k = 0; k < 16; ++k) {
        int b = barr[k];
        if (b >= 0) {
            int r = atomicAdd(&hist[b], 1);
            int p = lbase[b] + r;
            sorted[p] = (unsigned)varr[k];
            bId[p] = (unsigned short)b;
        }
    }
    __syncthreads();

    for (int i = tid; i < nval; i += 256) {
        int b = bId[i];
        pairs[gbase[b] + (i - lbase[b])] = sorted[i];
    }
}

// ---------------------------------------------------------------------------
// K3: per-bucket node sort (256 keys, 1 thread per key). cursor[b] now holds
// the bucket count. In-place rewrite of pairs -> node-sorted plain src ids +
// node_off (stride-257 layout with per-bucket sentinel).
// ---------------------------------------------------------------------------
__global__ __launch_bounds__(256) void k_nodesort(const int* __restrict__ cursor,
                                                  unsigned* __restrict__ pairs,
                                                  int* __restrict__ node_off) {
    __shared__ unsigned buf[SLAB];      // 18 KB
    __shared__ int hist[BNODES];
    __shared__ int cur[BNODES];
    __shared__ int t[256];

    int tid = threadIdx.x, b = blockIdx.x;
    int beg = b * SLAB;
    int cnt = cursor[b];

    hist[tid] = 0;
    __syncthreads();

    for (int i = tid; i < cnt; i += 256) {
        unsigned p = pairs[beg + i];
        buf[i] = p;
        atomicAdd(&hist[p & (BNODES - 1)], 1);
    }
    __syncthreads();

    int v = hist[tid];
    t[tid] = v;
    __syncthreads();
#pragma unroll
    for (int off = 1; off < 256; off <<= 1) {
        int x = (tid >= off) ? t[tid - off] : 0;
        __syncthreads();
        t[tid] += x;
        __syncthreads();
    }
    int excl = t[tid] - v;
    cur[tid] = excl;
    node_off[b * NOSTRIDE + tid] = beg + excl;
    if (tid == 0) node_off[b * NOSTRIDE + BNODES] = beg + cnt;  // sentinel
    __syncthreads();

    for (int i = tid; i < cnt; i += 256) {
        unsigned p = buf[i];
        int pos = atomicAdd(&cur[p & (BNODES - 1)], 1);
        pairs[beg + pos] = p >> BSHIFT;    // plain src id, node-sorted
    }
}

// ---------------------------------------------------------------------------
// K4: layer-1 aggregation: 64 nodes/block, 4 lanes/node, uint2 (8B) gathers,
// 8-deep unroll with 2-stage csr prefetch (next 8 indices load while current
// gathers are in flight). Register accumulation, fused bias+ReLU -> bf16 H1.
// ---------------------------------------------------------------------------
__global__ __launch_bounds__(256) void k_agg1(const int* __restrict__ node_off,
                                              const unsigned* __restrict__ csr,
                                              const uint2* __restrict__ Yu2,
                                              const float* __restrict__ bias1,
                                              uint2* __restrict__ H1u2) {
    int tid = threadIdx.x;
    int g = tid >> 2, c = tid & 3;
    int n = blockIdx.x * 64 + g;
    if (n >= N_NODES) return;
    int idx = n + (n >> 8);
    int beg = node_off[idx], end = node_off[idx + 1];

    float a[4] = {0.f, 0.f, 0.f, 0.f}, b[4] = {0.f, 0.f, 0.f, 0.f};
    int i = beg;
    unsigned s0, s1, s2, s3, s4, s5, s6, s7;
    if (i + 7 < end) {
        s0 = csr[i];     s1 = csr[i + 1]; s2 = csr[i + 2]; s3 = csr[i + 3];
        s4 = csr[i + 4]; s5 = csr[i + 5]; s6 = csr[i + 6]; s7 = csr[i + 7];
        while (true) {
            int ni = i + 8;
            unsigned t0 = 0, t1 = 0, t2 = 0, t3 = 0, t4 = 0, t5 = 0, t6 = 0, t7 = 0;
            bool more = (ni + 7 < end);
            if (more) {   // prefetch next batch before stalling on gathers
                t0 = csr[ni];     t1 = csr[ni + 1]; t2 = csr[ni + 2]; t3 = csr[ni + 3];
                t4 = csr[ni + 4]; t5 = csr[ni + 5]; t6 = csr[ni + 6]; t7 = csr[ni + 7];
            }
            uint2 w0 = Yu2[(size_t)s0 * 4 + c];
            uint2 w1 = Yu2[(size_t)s1 * 4 + c];
            uint2 w2 = Yu2[(size_t)s2 * 4 + c];
            uint2 w3 = Yu2[(size_t)s3 * 4 + c];
            uint2 w4 = Yu2[(size_t)s4 * 4 + c];
            uint2 w5 = Yu2[(size_t)s5 * 4 + c];
            uint2 w6 = Yu2[(size_t)s6 * 4 + c];
            uint2 w7 = Yu2[(size_t)s7 * 4 + c];
            acc4(a, w0); acc4(b, w1); acc4(a, w2); acc4(b, w3);
            acc4(a, w4); acc4(b, w5); acc4(a, w6); acc4(b, w7);
            i = ni;
            if (!more) break;
            s0 = t0; s1 = t1; s2 = t2; s3 = t3;
            s4 = t4; s5 = t5; s6 = t6; s7 = t7;
        }
    }
    for (; i < end; ++i) {
        uint2 w = Yu2[(size_t)csr[i] * 4 + c];
        acc4(a, w);
    }
    float f0 = a[0] + b[0] + bias1[c * 4 + 0];
    float f1 = a[1] + b[1] + bias1[c * 4 + 1];
    float f2 = a[2] + b[2] + bias1[c * 4 + 2];
    float f3 = a[3] + b[3] + bias1[c * 4 + 3];
    uint2 o;
    o.x = bf_pack(fmaxf(f0, 0.f), fmaxf(f1, 0.f));
    o.y = bf_pack(fmaxf(f2, 0.f), fmaxf(f3, 0.f));
    H1u2[(size_t)n * 4 + c] = o;
}

// ---------------------------------------------------------------------------
// K5: layer-2 aggregation (same gather structure) + fused mm2 epilogue.
// ---------------------------------------------------------------------------
__global__ __launch_bounds__(256) void k_agg2(const int* __restrict__ node_off,
                                              const unsigned* __restrict__ csr,
                                              const uint2* __restrict__ H1u2,
                                              const float* __restrict__ W2,
                                              const float* __restrict__ b2,
                                              float* __restrict__ out) {
    __shared__ float sacc[64][D_HID + 1];  // 4.4 KB
    __shared__ float sW2[D_HID * D_OUT];   // 2 KB
    __shared__ float sb2[D_OUT];
    int tid = threadIdx.x;
    for (int i2 = tid; i2 < D_HID * D_OUT; i2 += 256) sW2[i2] = W2[i2];
    if (tid < D_OUT) sb2[tid] = b2[tid];

    int g = tid >> 2, c = tid & 3;
    int n = blockIdx.x * 64 + g;

    float a[4] = {0.f, 0.f, 0.f, 0.f}, b[4] = {0.f, 0.f, 0.f, 0.f};
    if (n < N_NODES) {
        int idx = n + (n >> 8);
        int beg = node_off[idx], end = node_off[idx + 1];
        int i = beg;
        unsigned s0, s1, s2, s3, s4, s5, s6, s7;
        if (i + 7 < end) {
            s0 = csr[i];     s1 = csr[i + 1]; s2 = csr[i + 2]; s3 = csr[i + 3];
            s4 = csr[i + 4]; s5 = csr[i + 5]; s6 = csr[i + 6]; s7 = csr[i + 7];
            while (true) {
                int ni = i + 8;
                unsigned t0 = 0, t1 = 0, t2 = 0, t3 = 0, t4 = 0, t5 = 0, t6 = 0, t7 = 0;
                bool more = (ni + 7 < end);
                if (more) {
                    t0 = csr[ni];     t1 = csr[ni + 1]; t2 = csr[ni + 2]; t3 = csr[ni + 3];
                    t4 = csr[ni + 4]; t5 = csr[ni + 5]; t6 = csr[ni + 6]; t7 = csr[ni + 7];
                }
                uint2 w0 = H1u2[(size_t)s0 * 4 + c];
                uint2 w1 = H1u2[(size_t)s1 * 4 + c];
                uint2 w2 = H1u2[(size_t)s2 * 4 + c];
                uint2 w3 = H1u2[(size_t)s3 * 4 + c];
                uint2 w4 = H1u2[(size_t)s4 * 4 + c];
                uint2 w5 = H1u2[(size_t)s5 * 4 + c];
                uint2 w6 = H1u2[(size_t)s6 * 4 + c];
                uint2 w7 = H1u2[(size_t)s7 * 4 + c];
                acc4(a, w0); acc4(b, w1); acc4(a, w2); acc4(b, w3);
                acc4(a, w4); acc4(b, w5); acc4(a, w6); acc4(b, w7);
                i = ni;
                if (!more) break;
                s0 = t0; s1 = t1; s2 = t2; s3 = t3;
                s4 = t4; s5 = t5; s6 = t6; s7 = t7;
            }
        }
        for (; i < end; ++i) {
            uint2 w = H1u2[(size_t)csr[i] * 4 + c];
            acc4(a, w);
        }
    }
    sacc[g][c * 4 + 0] = a[0] + b[0];
    sacc[g][c * 4 + 1] = a[1] + b[1];
    sacc[g][c * 4 + 2] = a[2] + b[2];
    sacc[g][c * 4 + 3] = a[3] + b[3];
    __syncthreads();

    // mm2: 64 nodes x 32 outputs = 2048 -> 8 per thread
    for (int t2 = tid; t2 < 64 * D_OUT; t2 += 256) {
        int gg = t2 >> 5, o = t2 & 31;
        int node = blockIdx.x * 64 + gg;
        if (node < N_NODES) {
            float acc = sb2[o];
#pragma unroll
            for (int j = 0; j < D_HID; ++j)
                acc = fmaf(sacc[gg][j], sW2[j * D_OUT + o], acc);
            out[(size_t)node * D_OUT + o] = acc;
        }
    }
}

// ---------------------------------------------------------------------------
extern "C" void kernel_launch(void* const* d_in, const int* in_sizes, int n_in,
                              void* d_out, int out_size, void* d_ws, size_t ws_size,
                              hipStream_t stream) {
    const float* feat = (const float*)d_in[0];
    const int*   src  = (const int*)d_in[1];
    const int*   dst  = (const int*)d_in[2];
    const float* W1   = (const float*)d_in[3];
    const float* b1   = (const float*)d_in[4];
    const float* W2   = (const float*)d_in[5];
    const float* b2   = (const float*)d_in[6];
    float* out = (float*)d_out;

    // ws layout (~14.0 MB):
    //   [0        , 7206912 )  pairs/csr slabs (NB * SLAB u32)
    //   [7208960  , +3.2M   )  Yu   (bf16x16 rows, packed, 16B aligned)
    //   [10408960 , +3.2M   )  H1u  (bf16x16 rows, packed, 16B aligned)
    //   [13608960 , +1.6K   )  cursor   (NB ints, counts-relative)
    //   [13613056 , +402K   )  node_off (NB*257 ints)
    char* base = (char*)d_ws;
    unsigned* pairs    = (unsigned*)(base);
    unsigned* Yu       = (unsigned*)(base + 7208960);
    unsigned* H1u      = (unsigned*)(base + 10408960);
    int*      cursor   = (int*)(base + 13608960);
    int*      node_off = (int*)(base + 13613056);

    // K1: projection (2 nodes/thread, full occupancy) + cursor zeroing
    k_mm1        <<<MMBLOCKS, 256, 0, stream>>>(feat, W1, Yu, cursor);
    // K2: bucket-grouping counting sort into slabs
    k_sortscatter<<<SBLOCKS, 256, 0, stream>>>(src, dst, cursor, pairs);
    // K3: per-bucket node sort -> csr + node_off
    k_nodesort   <<<NB, 256, 0, stream>>>(cursor, pairs, node_off);
    // K4: layer-1 aggregation (fused bias+ReLU)
    k_agg1       <<<(N_NODES + 63) / 64, 256, 0, stream>>>(node_off, pairs,
                                                           (const uint2*)Yu, b1,
                                                           (uint2*)H1u);
    // K5: layer-2 aggregation + fused mm2
    k_agg2       <<<(N_NODES + 63) / 64, 256, 0, stream>>>(node_off, pairs,
                                                           (const uint2*)H1u, W2, b2, out);
}